// Round 1
// baseline (1074.517 us; speedup 1.0000x reference)
//
#include <hip/hip_runtime.h>
#include <hip/hip_bf16.h>
#include <math.h>

// Problem constants (from reference)
#define NN 50000
#define EE 800000
#define FIN 256
#define DD 150
#define HC 300        // H*C
#define CC 150
#define ET (EE + NN)  // edges + self loops = 850000
#define LN_EPS 1e-5f

// ---------------------------------------------------------------------------
// k1: idx = argmax(x, axis=1); h0 = emb[idx]   (one wave per node)
// ---------------------------------------------------------------------------
__global__ __launch_bounds__(256) void k_argmax_embed(
    const float* __restrict__ x, const float* __restrict__ emb,
    float* __restrict__ h0) {
  int node = blockIdx.x * 4 + (threadIdx.x >> 6);
  int lane = threadIdx.x & 63;
  if (node >= NN) return;
  const float* row = x + (size_t)node * FIN;
  float best = -INFINITY;
  int bidx = FIN;  // larger than any valid idx so any real value wins ties
  #pragma unroll
  for (int r = 0; r < FIN / 64; ++r) {
    int j = lane + 64 * r;
    float v = row[j];
    if (v > best || (v == best && j < bidx)) { best = v; bidx = j; }
  }
  #pragma unroll
  for (int off = 32; off > 0; off >>= 1) {
    float ov = __shfl_xor(best, off, 64);
    int   oi = __shfl_xor(bidx, off, 64);
    if (ov > best || (ov == best && oi < bidx)) { best = ov; bidx = oi; }
  }
  const float* erow = emb + (size_t)bidx * DD;
  float* orow = h0 + (size_t)node * DD;
  for (int j = lane; j < DD; j += 64) orow[j] = erow[j];
}

// ---------------------------------------------------------------------------
// k2: degree counts by dst (incl. self loops)
// ---------------------------------------------------------------------------
__global__ __launch_bounds__(256) void k_count(
    const int* __restrict__ ei, int* __restrict__ counts) {
  int et = blockIdx.x * blockDim.x + threadIdx.x;
  if (et >= ET) return;
  int d = (et < EE) ? ei[EE + et] : (et - EE);
  atomicAdd(&counts[d], 1);
}

// ---------------------------------------------------------------------------
// k3: exclusive scan of counts -> offsets[N+1]  (single block)
// ---------------------------------------------------------------------------
__global__ __launch_bounds__(1024) void k_scan(
    const int* __restrict__ counts, int* __restrict__ offsets) {
  __shared__ int buf[1024];
  __shared__ int s_carry;
  int tid = threadIdx.x;
  if (tid == 0) s_carry = 0;
  __syncthreads();
  for (int base = 0; base < NN; base += 1024) {
    int i = base + tid;
    int v = (i < NN) ? counts[i] : 0;
    int carry = s_carry;
    buf[tid] = v;
    __syncthreads();
    int sum = v;
    for (int off = 1; off < 1024; off <<= 1) {
      int t = (tid >= off) ? buf[tid - off] : 0;
      __syncthreads();
      sum += t;
      buf[tid] = sum;
      __syncthreads();
    }
    if (i < NN) offsets[i] = carry + sum - v;  // exclusive
    int total = buf[1023];
    __syncthreads();
    if (tid == 0) s_carry = carry + total;
    __syncthreads();
  }
  if (tid == 0) offsets[NN] = s_carry;  // == ET
}

// ---------------------------------------------------------------------------
// k4: scatter edges into CSR (by dst); store src per slot
// ---------------------------------------------------------------------------
__global__ __launch_bounds__(256) void k_scatter(
    const int* __restrict__ ei, const int* __restrict__ offsets,
    int* __restrict__ cursor, int* __restrict__ csr_src) {
  int et = blockIdx.x * blockDim.x + threadIdx.x;
  if (et >= ET) return;
  int s = (et < EE) ? ei[et] : (et - EE);
  int d = (et < EE) ? ei[EE + et] : (et - EE);
  int pos = offsets[d] + atomicAdd(&cursor[d], 1);
  csr_src[pos] = s;
}

// ---------------------------------------------------------------------------
// k5: hp = h @ W   (h: [N,K], W: [K,300]).  16 rows per block, 320 threads.
// ---------------------------------------------------------------------------
__global__ __launch_bounds__(320) void k_gemm(
    const float* __restrict__ h, const float* __restrict__ W,
    float* __restrict__ hp, int K) {
  __shared__ float sh[16 * 300];
  int j = threadIdx.x;
  int row0 = blockIdx.x * 16;
  int total = 16 * K;
  for (int idx = j; idx < total; idx += 320) {
    int r = idx / K, c = idx - r * K;
    int gr = row0 + r;
    sh[idx] = (gr < NN) ? h[(size_t)gr * K + c] : 0.f;
  }
  __syncthreads();
  if (j < HC) {
    float acc[16];
    #pragma unroll
    for (int m = 0; m < 16; ++m) acc[m] = 0.f;
    #pragma unroll 2
    for (int k = 0; k < K; ++k) {
      float w = W[(size_t)k * HC + j];
      #pragma unroll
      for (int m = 0; m < 16; ++m) acc[m] += sh[m * K + k] * w;
    }
    #pragma unroll
    for (int m = 0; m < 16; ++m) {
      int gr = row0 + m;
      if (gr < NN) hp[(size_t)gr * HC + j] = acc[m];
    }
  }
}

// ---------------------------------------------------------------------------
// k5b: al_s[n][h] = sum_c hp[n][h][c]*a_s[h][c]; same for al_d. One wave/node.
// ---------------------------------------------------------------------------
__global__ __launch_bounds__(256) void k_attn_coef(
    const float* __restrict__ hp, const float* __restrict__ a_s,
    const float* __restrict__ a_d, float* __restrict__ al_s,
    float* __restrict__ al_d) {
  int node = blockIdx.x * 4 + (threadIdx.x >> 6);
  int lane = threadIdx.x & 63;
  if (node >= NN) return;
  const float* row = hp + (size_t)node * HC;
  float s0 = 0, s1 = 0, d0 = 0, d1 = 0;
  #pragma unroll
  for (int r = 0; r < 5; ++r) {
    int j = lane + 64 * r;
    if (j < HC) {
      float v = row[j];
      float as = a_s[j], ad = a_d[j];
      if (j < CC) { s0 += v * as; d0 += v * ad; }
      else        { s1 += v * as; d1 += v * ad; }
    }
  }
  #pragma unroll
  for (int off = 32; off > 0; off >>= 1) {
    s0 += __shfl_xor(s0, off, 64);
    s1 += __shfl_xor(s1, off, 64);
    d0 += __shfl_xor(d0, off, 64);
    d1 += __shfl_xor(d1, off, 64);
  }
  if (lane == 0) {
    al_s[node * 2 + 0] = s0; al_s[node * 2 + 1] = s1;
    al_d[node * 2 + 0] = d0; al_d[node * 2 + 1] = d1;
  }
}

__device__ __forceinline__ float lrelu(float v, float sl) {
  return v >= 0.f ? v : sl * v;
}

// online-softmax lane-combine with -inf guards
__device__ __forceinline__ void sm_combine(float& m, float& s, float om, float os) {
  if (om > m) {            // m may be -inf: s==0, s*exp(-inf - om)=0
    s = s * expf(m - om) + os;
    m = om;
  } else if (os > 0.f) {   // om <= m, om finite (else os==0)
    s += os * expf(om - m);
  }
}

// ---------------------------------------------------------------------------
// k6: layer-1 aggregation + bias + LayerNorm + leaky(0.01).  One wave/node.
// ---------------------------------------------------------------------------
__global__ __launch_bounds__(256) void k_agg_ln(
    const float* __restrict__ hp, const float* __restrict__ al_s,
    const float* __restrict__ al_d, const int* __restrict__ offsets,
    const int* __restrict__ csr_src, const float* __restrict__ b1,
    const float* __restrict__ ln_g, const float* __restrict__ ln_b,
    float* __restrict__ h1) {
  int node = blockIdx.x * 4 + (threadIdx.x >> 6);
  int lane = threadIdx.x & 63;
  if (node >= NN) return;
  int off = offsets[node];
  int deg = offsets[node + 1] - off;
  float ald0 = al_d[node * 2 + 0], ald1 = al_d[node * 2 + 1];

  // pass A: online softmax stats per head
  float m0 = -INFINITY, s0 = 0.f, m1 = -INFINITY, s1 = 0.f;
  for (int i = lane; i < deg; i += 64) {
    int sn = csr_src[off + i];
    float e0 = lrelu(al_s[sn * 2 + 0] + ald0, 0.2f);
    float e1 = lrelu(al_s[sn * 2 + 1] + ald1, 0.2f);
    if (e0 > m0) { s0 = s0 * expf(m0 - e0) + 1.f; m0 = e0; } else s0 += expf(e0 - m0);
    if (e1 > m1) { s1 = s1 * expf(m1 - e1) + 1.f; m1 = e1; } else s1 += expf(e1 - m1);
  }
  #pragma unroll
  for (int o = 32; o > 0; o >>= 1) {
    float om0 = __shfl_xor(m0, o, 64), os0 = __shfl_xor(s0, o, 64);
    float om1 = __shfl_xor(m1, o, 64), os1 = __shfl_xor(s1, o, 64);
    sm_combine(m0, s0, om0, os0);
    sm_combine(m1, s1, om1, os1);
  }
  float inv0 = 1.f / s0, inv1 = 1.f / s1;

  // pass B: weighted feature aggregation
  float out[5] = {0.f, 0.f, 0.f, 0.f, 0.f};
  for (int i = 0; i < deg; ++i) {
    int sn = csr_src[off + i];
    float e0 = lrelu(al_s[sn * 2 + 0] + ald0, 0.2f);
    float e1 = lrelu(al_s[sn * 2 + 1] + ald1, 0.2f);
    float a0 = expf(e0 - m0) * inv0;
    float a1 = expf(e1 - m1) * inv1;
    const float* hps = hp + (size_t)sn * HC;
    #pragma unroll
    for (int r = 0; r < 5; ++r) {
      int j = lane + 64 * r;
      if (j < HC) out[r] += (j < CC ? a0 : a1) * hps[j];
    }
  }

  // epilogue: + b1, LayerNorm, leaky 0.01
  float part = 0.f;
  #pragma unroll
  for (int r = 0; r < 5; ++r) {
    int j = lane + 64 * r;
    if (j < HC) { out[r] += b1[j]; part += out[r]; }
  }
  #pragma unroll
  for (int o = 32; o > 0; o >>= 1) part += __shfl_xor(part, o, 64);
  float mu = part * (1.f / HC);
  float vp = 0.f;
  #pragma unroll
  for (int r = 0; r < 5; ++r) {
    int j = lane + 64 * r;
    if (j < HC) { float d = out[r] - mu; vp += d * d; }
  }
  #pragma unroll
  for (int o = 32; o > 0; o >>= 1) vp += __shfl_xor(vp, o, 64);
  float rstd = 1.f / sqrtf(vp * (1.f / HC) + LN_EPS);
  float* orow = h1 + (size_t)node * HC;
  #pragma unroll
  for (int r = 0; r < 5; ++r) {
    int j = lane + 64 * r;
    if (j < HC) {
      float v = (out[r] - mu) * rstd * ln_g[j] + ln_b[j];
      orow[j] = lrelu(v, 0.01f);
    }
  }
}

// ---------------------------------------------------------------------------
// k8: layer-2 aggregation + bias + leaky(0.01) + fc projection. One wave/node.
// ---------------------------------------------------------------------------
__global__ __launch_bounds__(256) void k_agg_fc(
    const float* __restrict__ hp, const float* __restrict__ al_s,
    const float* __restrict__ al_d, const int* __restrict__ offsets,
    const int* __restrict__ csr_src, const float* __restrict__ b2,
    const float* __restrict__ fc_w, const float* __restrict__ fc_b,
    float* __restrict__ outp) {
  int node = blockIdx.x * 4 + (threadIdx.x >> 6);
  int lane = threadIdx.x & 63;
  if (node >= NN) return;
  int off = offsets[node];
  int deg = offsets[node + 1] - off;
  float ald0 = al_d[node * 2 + 0], ald1 = al_d[node * 2 + 1];

  float m0 = -INFINITY, s0 = 0.f, m1 = -INFINITY, s1 = 0.f;
  for (int i = lane; i < deg; i += 64) {
    int sn = csr_src[off + i];
    float e0 = lrelu(al_s[sn * 2 + 0] + ald0, 0.2f);
    float e1 = lrelu(al_s[sn * 2 + 1] + ald1, 0.2f);
    if (e0 > m0) { s0 = s0 * expf(m0 - e0) + 1.f; m0 = e0; } else s0 += expf(e0 - m0);
    if (e1 > m1) { s1 = s1 * expf(m1 - e1) + 1.f; m1 = e1; } else s1 += expf(e1 - m1);
  }
  #pragma unroll
  for (int o = 32; o > 0; o >>= 1) {
    float om0 = __shfl_xor(m0, o, 64), os0 = __shfl_xor(s0, o, 64);
    float om1 = __shfl_xor(m1, o, 64), os1 = __shfl_xor(s1, o, 64);
    sm_combine(m0, s0, om0, os0);
    sm_combine(m1, s1, om1, os1);
  }
  float inv0 = 1.f / s0, inv1 = 1.f / s1;

  float out[5] = {0.f, 0.f, 0.f, 0.f, 0.f};
  for (int i = 0; i < deg; ++i) {
    int sn = csr_src[off + i];
    float e0 = lrelu(al_s[sn * 2 + 0] + ald0, 0.2f);
    float e1 = lrelu(al_s[sn * 2 + 1] + ald1, 0.2f);
    float a0 = expf(e0 - m0) * inv0;
    float a1 = expf(e1 - m1) * inv1;
    const float* hps = hp + (size_t)sn * HC;
    #pragma unroll
    for (int r = 0; r < 5; ++r) {
      int j = lane + 64 * r;
      if (j < HC) out[r] += (j < CC ? a0 : a1) * hps[j];
    }
  }

  // epilogue: + b2, leaky 0.01, dot with fc_w, + fc_b
  float acc = 0.f;
  #pragma unroll
  for (int r = 0; r < 5; ++r) {
    int j = lane + 64 * r;
    if (j < HC) {
      float v = lrelu(out[r] + b2[j], 0.01f);
      acc += v * fc_w[j];
    }
  }
  #pragma unroll
  for (int o = 32; o > 0; o >>= 1) acc += __shfl_xor(acc, o, 64);
  if (lane == 0) outp[node] = acc + fc_b[0];
}

// ---------------------------------------------------------------------------
static inline size_t align_up(size_t x, size_t a) { return (x + a - 1) & ~(a - 1); }

extern "C" void kernel_launch(void* const* d_in, const int* in_sizes, int n_in,
                              void* d_out, int out_size, void* d_ws, size_t ws_size,
                              hipStream_t stream) {
  const float* x    = (const float*)d_in[0];
  const int*   ei   = (const int*)d_in[1];
  // d_in[2] edge_weight: unused by reference
  const float* emb  = (const float*)d_in[3];
  const float* W1   = (const float*)d_in[4];
  const float* as1  = (const float*)d_in[5];
  const float* ad1  = (const float*)d_in[6];
  const float* b1   = (const float*)d_in[7];
  const float* ln_g = (const float*)d_in[8];
  const float* ln_b = (const float*)d_in[9];
  const float* W2   = (const float*)d_in[10];
  const float* as2  = (const float*)d_in[11];
  const float* ad2  = (const float*)d_in[12];
  const float* b2   = (const float*)d_in[13];
  const float* fc_w = (const float*)d_in[14];
  const float* fc_b = (const float*)d_in[15];
  float* outp = (float*)d_out;

  // workspace layout (h0 shares the h1 region: lifetimes are disjoint)
  char* ws = (char*)d_ws;
  size_t o = 0;
  size_t o_hp  = o; o = align_up(o + (size_t)NN * HC * 4, 256);   // 60 MB (both layers)
  size_t o_h1  = o; o = align_up(o + (size_t)NN * HC * 4, 256);   // 60 MB (h0 aliases)
  size_t o_als = o; o = align_up(o + (size_t)NN * 2 * 4, 256);
  size_t o_ald = o; o = align_up(o + (size_t)NN * 2 * 4, 256);
  size_t o_cnt = o; o = align_up(o + (size_t)NN * 4, 256);
  size_t o_cur = o; o = align_up(o + (size_t)NN * 4, 256);
  size_t o_off = o; o = align_up(o + (size_t)(NN + 1) * 4, 256);
  size_t o_csr = o; o = align_up(o + (size_t)ET * 4, 256);

  float* hp      = (float*)(ws + o_hp);
  float* h1      = (float*)(ws + o_h1);
  float* h0      = (float*)(ws + o_h1);  // alias: h0 dead before h1 written
  float* al_s    = (float*)(ws + o_als);
  float* al_d    = (float*)(ws + o_ald);
  int*   counts  = (int*)(ws + o_cnt);
  int*   cursor  = (int*)(ws + o_cur);
  int*   offsets = (int*)(ws + o_off);
  int*   csr_src = (int*)(ws + o_csr);

  // zero counts + cursor (adjacent regions)
  hipMemsetAsync(ws + o_cnt, 0, o_off - o_cnt, stream);

  const int nwave_blocks = (NN + 3) / 4;          // 12500
  const int edge_blocks  = (ET + 255) / 256;      // 3321
  const int gemm_blocks  = (NN + 15) / 16;        // 3125

  // embedding gather
  k_argmax_embed<<<nwave_blocks, 256, 0, stream>>>(x, emb, h0);

  // CSR build (shared by both layers)
  k_count<<<edge_blocks, 256, 0, stream>>>(ei, counts);
  k_scan<<<1, 1024, 0, stream>>>(counts, offsets);
  k_scatter<<<edge_blocks, 256, 0, stream>>>(ei, offsets, cursor, csr_src);

  // ---- layer 1 ----
  k_gemm<<<gemm_blocks, 320, 0, stream>>>(h0, W1, hp, DD);
  k_attn_coef<<<nwave_blocks, 256, 0, stream>>>(hp, as1, ad1, al_s, al_d);
  k_agg_ln<<<nwave_blocks, 256, 0, stream>>>(hp, al_s, al_d, offsets, csr_src,
                                             b1, ln_g, ln_b, h1);

  // ---- layer 2 ----
  k_gemm<<<gemm_blocks, 320, 0, stream>>>(h1, W2, hp, HC);
  k_attn_coef<<<nwave_blocks, 256, 0, stream>>>(hp, as2, ad2, al_s, al_d);
  k_agg_fc<<<nwave_blocks, 256, 0, stream>>>(hp, al_s, al_d, offsets, csr_src,
                                             b2, fc_w, fc_b, outp);
}

// Round 3
// 983.901 us; speedup vs baseline: 1.0921x; 1.0921x over previous
//
#include <hip/hip_runtime.h>
#include <hip/hip_bf16.h>
#include <math.h>

// Problem constants (from reference)
#define NN 50000
#define EE 800000
#define FIN 256
#define DD 150
#define HC 300        // H*C
#define CC 150
#define ET (EE + NN)  // edges + self loops = 850000
#define LN_EPS 1e-5f

// ---------------------------------------------------------------------------
// k1: idx = argmax(x, axis=1); h0 = emb[idx]   (one wave per node)
// ---------------------------------------------------------------------------
__global__ __launch_bounds__(256) void k_argmax_embed(
    const float* __restrict__ x, const float* __restrict__ emb,
    float* __restrict__ h0) {
  int node = blockIdx.x * 4 + (threadIdx.x >> 6);
  int lane = threadIdx.x & 63;
  if (node >= NN) return;
  const float* row = x + (size_t)node * FIN;
  float best = -INFINITY;
  int bidx = FIN;  // larger than any valid idx so any real value wins ties
  #pragma unroll
  for (int r = 0; r < FIN / 64; ++r) {
    int j = lane + 64 * r;
    float v = row[j];
    if (v > best || (v == best && j < bidx)) { best = v; bidx = j; }
  }
  #pragma unroll
  for (int off = 32; off > 0; off >>= 1) {
    float ov = __shfl_xor(best, off, 64);
    int   oi = __shfl_xor(bidx, off, 64);
    if (ov > best || (ov == best && oi < bidx)) { best = ov; bidx = oi; }
  }
  // copy emb row (150 floats = 75 float2, 8B-aligned: 600B row stride)
  const float2* e2 = (const float2*)(emb + (size_t)bidx * DD);
  float2* o2 = (float2*)(h0 + (size_t)node * DD);
  o2[lane] = e2[lane];                       // chunks 0..63
  if (lane < 11) o2[64 + lane] = e2[64 + lane];  // chunks 64..74
}

// ---------------------------------------------------------------------------
// k2: degree counts by dst (incl. self loops)
// ---------------------------------------------------------------------------
__global__ __launch_bounds__(256) void k_count(
    const int* __restrict__ ei, int* __restrict__ counts) {
  int et = blockIdx.x * blockDim.x + threadIdx.x;
  if (et >= ET) return;
  int d = (et < EE) ? ei[EE + et] : (et - EE);
  atomicAdd(&counts[d], 1);
}

// ---------------------------------------------------------------------------
// k3: exclusive scan of counts -> offsets[N+1].  Single block, one-pass:
// per-thread chunk sum -> 1024-wide LDS scan -> per-thread writeback.
// ---------------------------------------------------------------------------
__global__ __launch_bounds__(1024) void k_scan(
    const int* __restrict__ counts, int* __restrict__ offsets) {
  __shared__ int buf[1024];
  const int CH = 49;  // 1024*49 = 50176 >= NN
  int tid = threadIdx.x;
  int base = tid * CH;
  int lsum = 0;
  for (int c = 0; c < CH; ++c) {
    int i = base + c;
    if (i < NN) lsum += counts[i];
  }
  buf[tid] = lsum;
  __syncthreads();
  for (int off = 1; off < 1024; off <<= 1) {
    int t = (tid >= off) ? buf[tid - off] : 0;
    __syncthreads();
    buf[tid] += t;
    __syncthreads();
  }
  int incl = buf[tid];
  int run = incl - lsum;  // exclusive prefix of this chunk
  for (int c = 0; c < CH; ++c) {
    int i = base + c;
    if (i < NN) { offsets[i] = run; run += counts[i]; }
  }
  if (tid == 1023) offsets[NN] = incl;  // grand total == ET
}

// ---------------------------------------------------------------------------
// k4: scatter edges into CSR (by dst); store src per slot
// ---------------------------------------------------------------------------
__global__ __launch_bounds__(256) void k_scatter(
    const int* __restrict__ ei, const int* __restrict__ offsets,
    int* __restrict__ cursor, int* __restrict__ csr_src) {
  int et = blockIdx.x * blockDim.x + threadIdx.x;
  if (et >= ET) return;
  int s = (et < EE) ? ei[et] : (et - EE);
  int d = (et < EE) ? ei[EE + et] : (et - EE);
  int pos = offsets[d] + atomicAdd(&cursor[d], 1);
  csr_src[pos] = s;
}

// ---------------------------------------------------------------------------
// k5: register-tiled GEMM  hp = h @ W  (h: [N,K], W: [K,300]) with fused
// attention-coefficient epilogue:  al_s/al_d[n][h] = sum_c hp[n][h*C+c]*a[h][c]
// Block: 256 threads = 4 waves, 32 rows/block (8 rows/wave).
// Lane j owns cols {j, j+64, j+128, j+192, j+256} (masked to <300).
// Per k-step: 8 broadcast LDS reads + 5 coalesced W loads + 40 FMAs.
// ---------------------------------------------------------------------------
template <int K, int KT>
__global__ __launch_bounds__(256) void k_gemm_rt(
    const float* __restrict__ h, const float* __restrict__ W,
    const float* __restrict__ a_s, const float* __restrict__ a_d,
    float* __restrict__ hp, float* __restrict__ al_s,
    float* __restrict__ al_d) {
  __shared__ float sh[32][KT];
  int tid = threadIdx.x;
  int wave = tid >> 6;
  int lane = tid & 63;
  int row0 = blockIdx.x * 32;
  int wrow = row0 + wave * 8;

  float acc[8][5];
  #pragma unroll
  for (int m = 0; m < 8; ++m)
    #pragma unroll
    for (int r = 0; r < 5; ++r) acc[m][r] = 0.f;

  for (int k0 = 0; k0 < K; k0 += KT) {
    __syncthreads();
    for (int idx = tid; idx < 32 * KT; idx += 256) {
      int r = idx / KT, c = idx - r * KT;
      int gr = row0 + r;
      sh[r][c] = (gr < NN) ? h[(size_t)gr * K + k0 + c] : 0.f;
    }
    __syncthreads();
    #pragma unroll 5
    for (int k = 0; k < KT; ++k) {
      const float* wp = W + (size_t)(k0 + k) * HC + lane;
      float w[5];
      #pragma unroll
      for (int r = 0; r < 5; ++r) {
        int col = lane + 64 * r;
        w[r] = (col < HC) ? wp[64 * r] : 0.f;
      }
      #pragma unroll
      for (int m = 0; m < 8; ++m) {
        float hv = sh[wave * 8 + m][k];
        #pragma unroll
        for (int r = 0; r < 5; ++r) acc[m][r] += hv * w[r];
      }
    }
  }

  // per-lane attention vectors
  float as_r[5], ad_r[5];
  #pragma unroll
  for (int r = 0; r < 5; ++r) {
    int col = lane + 64 * r;
    as_r[r] = (col < HC) ? a_s[col] : 0.f;
    ad_r[r] = (col < HC) ? a_d[col] : 0.f;
  }

  #pragma unroll
  for (int m = 0; m < 8; ++m) {
    int gr = wrow + m;
    if (gr >= NN) continue;
    float s0 = 0.f, s1 = 0.f, d0 = 0.f, d1 = 0.f;
    float* orow = hp + (size_t)gr * HC;
    #pragma unroll
    for (int r = 0; r < 5; ++r) {
      int col = lane + 64 * r;
      if (col < HC) {
        float v = acc[m][r];
        orow[col] = v;
        if (col < CC) { s0 += v * as_r[r]; d0 += v * ad_r[r]; }
        else          { s1 += v * as_r[r]; d1 += v * ad_r[r]; }
      }
    }
    #pragma unroll
    for (int o = 32; o > 0; o >>= 1) {
      s0 += __shfl_xor(s0, o, 64);
      s1 += __shfl_xor(s1, o, 64);
      d0 += __shfl_xor(d0, o, 64);
      d1 += __shfl_xor(d1, o, 64);
    }
    if (lane == 0) {
      al_s[gr * 2 + 0] = s0; al_s[gr * 2 + 1] = s1;
      al_d[gr * 2 + 0] = d0; al_d[gr * 2 + 1] = d1;
    }
  }
}

__device__ __forceinline__ float lrelu(float v, float sl) {
  return v >= 0.f ? v : sl * v;
}

// online-softmax lane-combine with -inf guards
__device__ __forceinline__ void sm_combine(float& m, float& s, float om, float os) {
  if (om > m) {
    s = s * expf(m - om) + os;
    m = om;
  } else if (os > 0.f) {
    s += os * expf(om - m);
  }
}

// softmax stats (pass A) shared by both aggregation kernels
__device__ __forceinline__ void softmax_stats(
    const float2* __restrict__ al2, const int* __restrict__ csr_src,
    int off, int deg, int lane, float ald0, float ald1,
    float& m0, float& s0, float& m1, float& s1) {
  m0 = -INFINITY; s0 = 0.f; m1 = -INFINITY; s1 = 0.f;
  for (int i = lane; i < deg; i += 64) {
    int sn = csr_src[off + i];
    float2 av = al2[sn];
    float e0 = lrelu(av.x + ald0, 0.2f);
    float e1 = lrelu(av.y + ald1, 0.2f);
    if (e0 > m0) { s0 = s0 * expf(m0 - e0) + 1.f; m0 = e0; } else s0 += expf(e0 - m0);
    if (e1 > m1) { s1 = s1 * expf(m1 - e1) + 1.f; m1 = e1; } else s1 += expf(e1 - m1);
  }
  #pragma unroll
  for (int o = 32; o > 0; o >>= 1) {
    float om0 = __shfl_xor(m0, o, 64), os0 = __shfl_xor(s0, o, 64);
    float om1 = __shfl_xor(m1, o, 64), os1 = __shfl_xor(s1, o, 64);
    sm_combine(m0, s0, om0, os0);
    sm_combine(m1, s1, om1, os1);
  }
}

// weighted aggregation (pass B). Lane j owns float4 chunk j (cols 4j..4j+3)
// and chunk 64+j for j<11 (cols 256+4j..). Chunk-1 cols are all >= 150 (head 1).
__device__ __forceinline__ void aggregate(
    const float4* __restrict__ hp4, const float2* __restrict__ al2,
    const int* __restrict__ csr_src, int off, int deg, int lane,
    float ald0, float ald1, float m0, float inv0, float m1, float inv1,
    float4& o0, float4& o1) {
  o0 = make_float4(0.f, 0.f, 0.f, 0.f);
  o1 = make_float4(0.f, 0.f, 0.f, 0.f);
  int c0 = lane * 4;
  bool h0x = c0 + 0 < CC, h0y = c0 + 1 < CC, h0z = c0 + 2 < CC, h0w = c0 + 3 < CC;
  int sn = csr_src[off];
  float2 av = al2[sn];
  for (int i = 0; i < deg; ++i) {
    int nsn = 0; float2 nav = make_float2(0.f, 0.f);
    if (i + 1 < deg) { nsn = csr_src[off + i + 1]; nav = al2[nsn]; }
    float e0 = lrelu(av.x + ald0, 0.2f);
    float e1 = lrelu(av.y + ald1, 0.2f);
    float a0 = expf(e0 - m0) * inv0;
    float a1 = expf(e1 - m1) * inv1;
    const float4* rp = hp4 + (size_t)sn * (HC / 4);
    float4 v0 = rp[lane];
    float w0x = h0x ? a0 : a1, w0y = h0y ? a0 : a1;
    float w0z = h0z ? a0 : a1, w0w = h0w ? a0 : a1;
    o0.x += v0.x * w0x; o0.y += v0.y * w0y;
    o0.z += v0.z * w0z; o0.w += v0.w * w0w;
    if (lane < 11) {
      float4 v1 = rp[64 + lane];
      o1.x += v1.x * a1; o1.y += v1.y * a1;
      o1.z += v1.z * a1; o1.w += v1.w * a1;
    }
    sn = nsn; av = nav;
  }
}

// ---------------------------------------------------------------------------
// k6: layer-1 aggregation + bias + LayerNorm + leaky(0.01).  One wave/node.
// ---------------------------------------------------------------------------
__global__ __launch_bounds__(256) void k_agg_ln(
    const float* __restrict__ hp, const float* __restrict__ al_s,
    const float* __restrict__ al_d, const int* __restrict__ offsets,
    const int* __restrict__ csr_src, const float* __restrict__ b1,
    const float* __restrict__ ln_g, const float* __restrict__ ln_b,
    float* __restrict__ h1) {
  int node = blockIdx.x * 4 + (threadIdx.x >> 6);
  int lane = threadIdx.x & 63;
  if (node >= NN) return;
  int off = offsets[node];
  int deg = offsets[node + 1] - off;
  const float2* al2 = (const float2*)al_s;
  float2 aldv = ((const float2*)al_d)[node];
  float ald0 = aldv.x, ald1 = aldv.y;

  float m0, s0, m1, s1;
  softmax_stats(al2, csr_src, off, deg, lane, ald0, ald1, m0, s0, m1, s1);
  float inv0 = 1.f / s0, inv1 = 1.f / s1;

  float4 o0, o1;
  aggregate((const float4*)hp, al2, csr_src, off, deg, lane,
            ald0, ald1, m0, inv0, m1, inv1, o0, o1);

  // + b1
  const float4* b14 = (const float4*)b1;
  float4 bb = b14[lane];
  o0.x += bb.x; o0.y += bb.y; o0.z += bb.z; o0.w += bb.w;
  if (lane < 11) {
    float4 bc = b14[64 + lane];
    o1.x += bc.x; o1.y += bc.y; o1.z += bc.z; o1.w += bc.w;
  }
  // LayerNorm over 300 cols
  float part = o0.x + o0.y + o0.z + o0.w;
  if (lane < 11) part += o1.x + o1.y + o1.z + o1.w;
  #pragma unroll
  for (int o = 32; o > 0; o >>= 1) part += __shfl_xor(part, o, 64);
  float mu = part * (1.f / HC);
  float vp = (o0.x - mu) * (o0.x - mu) + (o0.y - mu) * (o0.y - mu) +
             (o0.z - mu) * (o0.z - mu) + (o0.w - mu) * (o0.w - mu);
  if (lane < 11)
    vp += (o1.x - mu) * (o1.x - mu) + (o1.y - mu) * (o1.y - mu) +
          (o1.z - mu) * (o1.z - mu) + (o1.w - mu) * (o1.w - mu);
  #pragma unroll
  for (int o = 32; o > 0; o >>= 1) vp += __shfl_xor(vp, o, 64);
  float rstd = 1.f / sqrtf(vp * (1.f / HC) + LN_EPS);

  const float4* g4 = (const float4*)ln_g;
  const float4* lb4 = (const float4*)ln_b;
  float4* h14 = (float4*)(h1 + (size_t)node * HC);
  float4 g = g4[lane], lb = lb4[lane], w;
  w.x = lrelu((o0.x - mu) * rstd * g.x + lb.x, 0.01f);
  w.y = lrelu((o0.y - mu) * rstd * g.y + lb.y, 0.01f);
  w.z = lrelu((o0.z - mu) * rstd * g.z + lb.z, 0.01f);
  w.w = lrelu((o0.w - mu) * rstd * g.w + lb.w, 0.01f);
  h14[lane] = w;
  if (lane < 11) {
    float4 g1 = g4[64 + lane], lb1 = lb4[64 + lane], w1;
    w1.x = lrelu((o1.x - mu) * rstd * g1.x + lb1.x, 0.01f);
    w1.y = lrelu((o1.y - mu) * rstd * g1.y + lb1.y, 0.01f);
    w1.z = lrelu((o1.z - mu) * rstd * g1.z + lb1.z, 0.01f);
    w1.w = lrelu((o1.w - mu) * rstd * g1.w + lb1.w, 0.01f);
    h14[64 + lane] = w1;
  }
}

// ---------------------------------------------------------------------------
// k8: layer-2 aggregation + bias + leaky(0.01) + fc projection. One wave/node.
// ---------------------------------------------------------------------------
__global__ __launch_bounds__(256) void k_agg_fc(
    const float* __restrict__ hp, const float* __restrict__ al_s,
    const float* __restrict__ al_d, const int* __restrict__ offsets,
    const int* __restrict__ csr_src, const float* __restrict__ b2,
    const float* __restrict__ fc_w, const float* __restrict__ fc_b,
    float* __restrict__ outp) {
  int node = blockIdx.x * 4 + (threadIdx.x >> 6);
  int lane = threadIdx.x & 63;
  if (node >= NN) return;
  int off = offsets[node];
  int deg = offsets[node + 1] - off;
  const float2* al2 = (const float2*)al_s;
  float2 aldv = ((const float2*)al_d)[node];
  float ald0 = aldv.x, ald1 = aldv.y;

  float m0, s0, m1, s1;
  softmax_stats(al2, csr_src, off, deg, lane, ald0, ald1, m0, s0, m1, s1);
  float inv0 = 1.f / s0, inv1 = 1.f / s1;

  float4 o0, o1;
  aggregate((const float4*)hp, al2, csr_src, off, deg, lane,
            ald0, ald1, m0, inv0, m1, inv1, o0, o1);

  // epilogue: + b2, leaky 0.01, dot with fc_w, + fc_b
  const float4* b24 = (const float4*)b2;
  const float4* f4 = (const float4*)fc_w;
  float4 bb = b24[lane], fw = f4[lane];
  float acc = lrelu(o0.x + bb.x, 0.01f) * fw.x +
              lrelu(o0.y + bb.y, 0.01f) * fw.y +
              lrelu(o0.z + bb.z, 0.01f) * fw.z +
              lrelu(o0.w + bb.w, 0.01f) * fw.w;
  if (lane < 11) {
    float4 bc = b24[64 + lane], fc = f4[64 + lane];
    acc += lrelu(o1.x + bc.x, 0.01f) * fc.x +
           lrelu(o1.y + bc.y, 0.01f) * fc.y +
           lrelu(o1.z + bc.z, 0.01f) * fc.z +
           lrelu(o1.w + bc.w, 0.01f) * fc.w;
  }
  #pragma unroll
  for (int o = 32; o > 0; o >>= 1) acc += __shfl_xor(acc, o, 64);
  if (lane == 0) outp[node] = acc + fc_b[0];
}

// ---------------------------------------------------------------------------
static inline size_t align_up(size_t x, size_t a) { return (x + a - 1) & ~(a - 1); }

extern "C" void kernel_launch(void* const* d_in, const int* in_sizes, int n_in,
                              void* d_out, int out_size, void* d_ws, size_t ws_size,
                              hipStream_t stream) {
  const float* x    = (const float*)d_in[0];
  const int*   ei   = (const int*)d_in[1];
  // d_in[2] edge_weight: unused by reference
  const float* emb  = (const float*)d_in[3];
  const float* W1   = (const float*)d_in[4];
  const float* as1  = (const float*)d_in[5];
  const float* ad1  = (const float*)d_in[6];
  const float* b1   = (const float*)d_in[7];
  const float* ln_g = (const float*)d_in[8];
  const float* ln_b = (const float*)d_in[9];
  const float* W2   = (const float*)d_in[10];
  const float* as2  = (const float*)d_in[11];
  const float* ad2  = (const float*)d_in[12];
  const float* b2   = (const float*)d_in[13];
  const float* fc_w = (const float*)d_in[14];
  const float* fc_b = (const float*)d_in[15];
  float* outp = (float*)d_out;

  // workspace layout (h0 shares the h1 region: lifetimes are disjoint)
  char* ws = (char*)d_ws;
  size_t o = 0;
  size_t o_hp  = o; o = align_up(o + (size_t)NN * HC * 4, 256);   // 60 MB (both layers)
  size_t o_h1  = o; o = align_up(o + (size_t)NN * HC * 4, 256);   // 60 MB (h0 aliases)
  size_t o_als = o; o = align_up(o + (size_t)NN * 2 * 4, 256);
  size_t o_ald = o; o = align_up(o + (size_t)NN * 2 * 4, 256);
  size_t o_cnt = o; o = align_up(o + (size_t)NN * 4, 256);
  size_t o_cur = o; o = align_up(o + (size_t)NN * 4, 256);
  size_t o_off = o; o = align_up(o + (size_t)(NN + 1) * 4, 256);
  size_t o_csr = o; o = align_up(o + (size_t)ET * 4, 256);

  float* hp      = (float*)(ws + o_hp);
  float* h1      = (float*)(ws + o_h1);
  float* h0      = (float*)(ws + o_h1);  // alias: h0 dead before h1 written
  float* al_s    = (float*)(ws + o_als);
  float* al_d    = (float*)(ws + o_ald);
  int*   counts  = (int*)(ws + o_cnt);
  int*   cursor  = (int*)(ws + o_cur);
  int*   offsets = (int*)(ws + o_off);
  int*   csr_src = (int*)(ws + o_csr);

  // zero counts + cursor (adjacent regions)
  hipMemsetAsync(ws + o_cnt, 0, o_off - o_cnt, stream);

  const int nwave_blocks = (NN + 3) / 4;          // 12500
  const int edge_blocks  = (ET + 255) / 256;      // 3321
  const int gemm_blocks  = (NN + 31) / 32;        // 1563

  // embedding gather
  k_argmax_embed<<<nwave_blocks, 256, 0, stream>>>(x, emb, h0);

  // CSR build (shared by both layers)
  k_count<<<edge_blocks, 256, 0, stream>>>(ei, counts);
  k_scan<<<1, 1024, 0, stream>>>(counts, offsets);
  k_scatter<<<edge_blocks, 256, 0, stream>>>(ei, offsets, cursor, csr_src);

  // ---- layer 1 ----
  k_gemm_rt<DD, 75><<<gemm_blocks, 256, 0, stream>>>(h0, W1, as1, ad1,
                                                     hp, al_s, al_d);
  k_agg_ln<<<nwave_blocks, 256, 0, stream>>>(hp, al_s, al_d, offsets, csr_src,
                                             b1, ln_g, ln_b, h1);

  // ---- layer 2 ----
  k_gemm_rt<HC, 75><<<gemm_blocks, 256, 0, stream>>>(h1, W2, as2, ad2,
                                                     hp, al_s, al_d);
  k_agg_fc<<<nwave_blocks, 256, 0, stream>>>(hp, al_s, al_d, offsets, csr_src,
                                             b2, fc_w, fc_b, outp);
}

// Round 4
// 800.238 us; speedup vs baseline: 1.3427x; 1.2295x over previous
//
#include <hip/hip_runtime.h>
#include <hip/hip_bf16.h>
#include <math.h>

// Problem constants (from reference)
#define NN 50000
#define EE 800000
#define FIN 256
#define DD 150
#define HC 300        // H*C
#define CC 150
#define ET (EE + NN)  // edges + self loops = 850000
#define LN_EPS 1e-5f
#define NT 19         // col tiles of 16 covering 300 (304)

typedef __attribute__((ext_vector_type(8))) short short8;   // 8 bf16 (4 VGPR)
typedef __attribute__((ext_vector_type(4))) float f32x4;    // MFMA C/D frag

static __device__ __forceinline__ unsigned short f2bf(float f) {
  unsigned int u = __float_as_uint(f);
  u += 0x7FFFu + ((u >> 16) & 1u);   // round-to-nearest-even
  return (unsigned short)(u >> 16);
}

// ---------------------------------------------------------------------------
// k1: idx = argmax(x, axis=1); h0 = emb[idx]   (one wave per node)
// ---------------------------------------------------------------------------
__global__ __launch_bounds__(256) void k_argmax_embed(
    const float* __restrict__ x, const float* __restrict__ emb,
    float* __restrict__ h0) {
  int node = blockIdx.x * 4 + (threadIdx.x >> 6);
  int lane = threadIdx.x & 63;
  if (node >= NN) return;
  const float* row = x + (size_t)node * FIN;
  float best = -INFINITY;
  int bidx = FIN;
  #pragma unroll
  for (int r = 0; r < FIN / 64; ++r) {
    int j = lane + 64 * r;
    float v = row[j];
    if (v > best || (v == best && j < bidx)) { best = v; bidx = j; }
  }
  #pragma unroll
  for (int off = 32; off > 0; off >>= 1) {
    float ov = __shfl_xor(best, off, 64);
    int   oi = __shfl_xor(bidx, off, 64);
    if (ov > best || (ov == best && oi < bidx)) { best = ov; bidx = oi; }
  }
  const float2* e2 = (const float2*)(emb + (size_t)bidx * DD);
  float2* o2 = (float2*)(h0 + (size_t)node * DD);
  o2[lane] = e2[lane];
  if (lane < 11) o2[64 + lane] = e2[64 + lane];
}

// ---------------------------------------------------------------------------
// CSR build (count / scan / scatter)
// ---------------------------------------------------------------------------
__global__ __launch_bounds__(256) void k_count(
    const int* __restrict__ ei, int* __restrict__ counts) {
  int et = blockIdx.x * blockDim.x + threadIdx.x;
  if (et >= ET) return;
  int d = (et < EE) ? ei[EE + et] : (et - EE);
  atomicAdd(&counts[d], 1);
}

__global__ __launch_bounds__(1024) void k_scan(
    const int* __restrict__ counts, int* __restrict__ offsets) {
  __shared__ int buf[1024];
  const int CH = 49;  // 1024*49 >= NN
  int tid = threadIdx.x;
  int base = tid * CH;
  int lsum = 0;
  for (int c = 0; c < CH; ++c) {
    int i = base + c;
    if (i < NN) lsum += counts[i];
  }
  buf[tid] = lsum;
  __syncthreads();
  for (int off = 1; off < 1024; off <<= 1) {
    int t = (tid >= off) ? buf[tid - off] : 0;
    __syncthreads();
    buf[tid] += t;
    __syncthreads();
  }
  int incl = buf[tid];
  int run = incl - lsum;
  for (int c = 0; c < CH; ++c) {
    int i = base + c;
    if (i < NN) { offsets[i] = run; run += counts[i]; }
  }
  if (tid == 1023) offsets[NN] = incl;
}

__global__ __launch_bounds__(256) void k_scatter(
    const int* __restrict__ ei, const int* __restrict__ offsets,
    int* __restrict__ cursor, int* __restrict__ csr_src) {
  int et = blockIdx.x * blockDim.x + threadIdx.x;
  if (et >= ET) return;
  int s = (et < EE) ? ei[et] : (et - EE);
  int d = (et < EE) ? ei[EE + et] : (et - EE);
  int pos = offsets[d] + atomicAdd(&cursor[d], 1);
  csr_src[pos] = s;
}

// ---------------------------------------------------------------------------
// k_pack_w: W [K][300] f32 -> Wp bf16 B-fragment layout [ks][ct][lane][8]
// frag element: Wp[((ks*NT+ct)*64+l)*8 + j] = W[ks*32+(l>>4)*8+j][ct*16+(l&15)]
// ---------------------------------------------------------------------------
__global__ __launch_bounds__(64) void k_pack_w(
    const float* __restrict__ W, unsigned short* __restrict__ Wp, int K) {
  int ks = blockIdx.x / NT, ct = blockIdx.x % NT;
  int l = threadIdx.x;
  int col = ct * 16 + (l & 15);
  int kb = ks * 32 + ((l >> 4) << 3);
  unsigned short v[8];
  #pragma unroll
  for (int j = 0; j < 8; ++j) {
    int k = kb + j;
    float f = (k < K && col < HC) ? W[(size_t)k * HC + col] : 0.f;
    v[j] = f2bf(f);
  }
  *(ulonglong2*)(Wp + ((size_t)blockIdx.x * 64 + l) * 8) = *(ulonglong2*)v;
}

// ---------------------------------------------------------------------------
// k_wa: va[0..3][K] = [W a_s(h0) | W a_s(h1) | W a_d(h0) | W a_d(h1)]
// al = hp . a  ==  h . (W a)  -- exact f32, decoupled from bf16 GEMM
// ---------------------------------------------------------------------------
__global__ __launch_bounds__(64) void k_wa(
    const float* __restrict__ W, const float* __restrict__ a_s,
    const float* __restrict__ a_d, float* __restrict__ va, int K) {
  int k = blockIdx.x * 64 + threadIdx.x;
  if (k >= K) return;
  const float* wr = W + (size_t)k * HC;
  float s0 = 0, s1 = 0, d0 = 0, d1 = 0;
  for (int c = 0; c < CC; ++c) {
    float w0 = wr[c], w1 = wr[CC + c];
    s0 += w0 * a_s[c];      s1 += w1 * a_s[CC + c];
    d0 += w0 * a_d[c];      d1 += w1 * a_d[CC + c];
  }
  va[k] = s0; va[K + k] = s1; va[2 * K + k] = d0; va[3 * K + k] = d1;
}

// ---------------------------------------------------------------------------
// k_gemm_mfma: hp = h @ W via mfma_f32_16x16x32_bf16.
// Block 256 = 4 waves, 64 rows/block; wave w -> rows [w*16, w*16+16).
// A staged f32->bf16 in LDS (row stride RS, +8 pad -> 2-way conflict = free).
// B frags one 16B L2 load each from pre-packed Wp. hp output stays f32.
// ---------------------------------------------------------------------------
template <int K>
__global__ __launch_bounds__(256) void k_gemm_mfma(
    const float* __restrict__ h, const unsigned short* __restrict__ Wp,
    float* __restrict__ hp) {
  constexpr int KS = (K + 31) / 32;
  constexpr int RS = KS * 32 + 8;
  __shared__ unsigned short sh[64 * RS];
  int tid = threadIdx.x;
  int wave = tid >> 6, lane = tid & 63;
  int rows0 = blockIdx.x * 64;

  // stage h -> LDS bf16 (float2 loads; clamp OOB rows, stores masked later)
  constexpr int K2 = K / 2;
  for (int i = tid; i < 64 * K2; i += 256) {
    int r = i / K2, c2 = i - r * K2;
    int gr = rows0 + r; if (gr >= NN) gr = NN - 1;
    float2 hv = *(const float2*)(h + (size_t)gr * K + c2 * 2);
    unsigned int packed =
        (unsigned int)f2bf(hv.x) | ((unsigned int)f2bf(hv.y) << 16);
    *(unsigned int*)&sh[r * RS + c2 * 2] = packed;
  }
  constexpr int TL2 = (KS * 32 - K) / 2;  // K-tail zero fill
  if (TL2 > 0) {
    for (int i = tid; i < 64 * TL2; i += 256) {
      int r = i / TL2, c2 = i - r * TL2;
      *(unsigned int*)&sh[r * RS + K + c2 * 2] = 0u;
    }
  }
  __syncthreads();

  f32x4 acc[NT];
  #pragma unroll
  for (int ct = 0; ct < NT; ++ct) acc[ct] = f32x4{0.f, 0.f, 0.f, 0.f};

  const unsigned short* abase = &sh[(wave * 16 + (lane & 15)) * RS + (lane >> 4) * 8];
  const short8* wb = (const short8*)Wp;

  short8 a = *(const short8*)abase;
  #pragma unroll 1
  for (int ks = 0; ks < KS; ++ks) {
    short8 an = (ks + 1 < KS) ? *(const short8*)(abase + (ks + 1) * 32) : a;
    #pragma unroll
    for (int ct = 0; ct < NT; ++ct) {
      short8 b = wb[(ks * NT + ct) * 64 + lane];
      acc[ct] = __builtin_amdgcn_mfma_f32_16x16x32_bf16(a, b, acc[ct], 0, 0, 0);
    }
    a = an;
  }

  // C/D layout: col = lane&15, row = (lane>>4)*4 + j   [m89-verified]
  int grow = rows0 + wave * 16 + ((lane >> 4) << 2);
  int cbase = lane & 15;
  #pragma unroll
  for (int ct = 0; ct < NT; ++ct) {
    int col = ct * 16 + cbase;
    if (col < HC) {
      #pragma unroll
      for (int j = 0; j < 4; ++j) {
        int gr = grow + j;
        if (gr < NN) hp[(size_t)gr * HC + col] = acc[ct][j];
      }
    }
  }
}

// ---------------------------------------------------------------------------
// k_attn_va: al_s/al_d[n][h] = h[n] . va[.]   (one wave per node, exact f32)
// ---------------------------------------------------------------------------
template <int K>
__global__ __launch_bounds__(256) void k_attn_va(
    const float* __restrict__ h, const float* __restrict__ va,
    float* __restrict__ al_s, float* __restrict__ al_d) {
  int node = blockIdx.x * 4 + (threadIdx.x >> 6);
  int lane = threadIdx.x & 63;
  if (node >= NN) return;
  const float* hr = h + (size_t)node * K;
  float s0 = 0, s1 = 0, d0 = 0, d1 = 0;
  for (int k = lane; k < K; k += 64) {
    float hv = hr[k];
    s0 += hv * va[k];         s1 += hv * va[K + k];
    d0 += hv * va[2 * K + k]; d1 += hv * va[3 * K + k];
  }
  #pragma unroll
  for (int o = 32; o > 0; o >>= 1) {
    s0 += __shfl_xor(s0, o, 64); s1 += __shfl_xor(s1, o, 64);
    d0 += __shfl_xor(d0, o, 64); d1 += __shfl_xor(d1, o, 64);
  }
  if (lane == 0) {
    al_s[node * 2 + 0] = s0; al_s[node * 2 + 1] = s1;
    al_d[node * 2 + 0] = d0; al_d[node * 2 + 1] = d1;
  }
}

__device__ __forceinline__ float lrelu(float v, float sl) {
  return v >= 0.f ? v : sl * v;
}

__device__ __forceinline__ void sm_combine(float& m, float& s, float om, float os) {
  if (om > m) {
    s = s * expf(m - om) + os;
    m = om;
  } else if (os > 0.f) {
    s += os * expf(om - m);
  }
}

__device__ __forceinline__ void softmax_stats(
    const float2* __restrict__ al2, const int* __restrict__ csr_src,
    int off, int deg, int lane, float ald0, float ald1,
    float& m0, float& s0, float& m1, float& s1) {
  m0 = -INFINITY; s0 = 0.f; m1 = -INFINITY; s1 = 0.f;
  for (int i = lane; i < deg; i += 64) {
    int sn = csr_src[off + i];
    float2 av = al2[sn];
    float e0 = lrelu(av.x + ald0, 0.2f);
    float e1 = lrelu(av.y + ald1, 0.2f);
    if (e0 > m0) { s0 = s0 * expf(m0 - e0) + 1.f; m0 = e0; } else s0 += expf(e0 - m0);
    if (e1 > m1) { s1 = s1 * expf(m1 - e1) + 1.f; m1 = e1; } else s1 += expf(e1 - m1);
  }
  #pragma unroll
  for (int o = 32; o > 0; o >>= 1) {
    float om0 = __shfl_xor(m0, o, 64), os0 = __shfl_xor(s0, o, 64);
    float om1 = __shfl_xor(m1, o, 64), os1 = __shfl_xor(s1, o, 64);
    sm_combine(m0, s0, om0, os0);
    sm_combine(m1, s1, om1, os1);
  }
}

// weighted aggregation with 1-deep hp-row prefetch (double-buffered).
// Lane j owns float4 chunk j (cols 4j..4j+3) and chunk 64+j for j<11.
__device__ __forceinline__ void aggregate(
    const float4* __restrict__ hp4, const float2* __restrict__ al2,
    const int* __restrict__ csr_src, int off, int deg, int lane,
    float ald0, float ald1, float m0, float inv0, float m1, float inv1,
    float4& o0, float4& o1) {
  o0 = make_float4(0.f, 0.f, 0.f, 0.f);
  o1 = make_float4(0.f, 0.f, 0.f, 0.f);
  int c0 = lane * 4;
  bool h0x = c0 + 0 < CC, h0y = c0 + 1 < CC, h0z = c0 + 2 < CC, h0w = c0 + 3 < CC;
  bool hi = lane < 11;
  int sn = csr_src[off];
  float2 av = al2[sn];
  const float4* rp = hp4 + (size_t)sn * (HC / 4);
  float4 v0 = rp[lane];
  float4 v1 = hi ? rp[64 + lane] : make_float4(0.f, 0.f, 0.f, 0.f);
  for (int i = 0; i < deg; ++i) {
    float2 nav = make_float2(0.f, 0.f);
    float4 nv0 = make_float4(0.f, 0.f, 0.f, 0.f);
    float4 nv1 = make_float4(0.f, 0.f, 0.f, 0.f);
    if (i + 1 < deg) {   // issue next row's loads before current math
      int nsn = csr_src[off + i + 1];
      nav = al2[nsn];
      const float4* nrp = hp4 + (size_t)nsn * (HC / 4);
      nv0 = nrp[lane];
      if (hi) nv1 = nrp[64 + lane];
    }
    float e0 = lrelu(av.x + ald0, 0.2f);
    float e1 = lrelu(av.y + ald1, 0.2f);
    float a0 = expf(e0 - m0) * inv0;
    float a1 = expf(e1 - m1) * inv1;
    o0.x += v0.x * (h0x ? a0 : a1); o0.y += v0.y * (h0y ? a0 : a1);
    o0.z += v0.z * (h0z ? a0 : a1); o0.w += v0.w * (h0w ? a0 : a1);
    o1.x += v1.x * a1; o1.y += v1.y * a1;
    o1.z += v1.z * a1; o1.w += v1.w * a1;
    av = nav; v0 = nv0; v1 = nv1;
  }
}

// ---------------------------------------------------------------------------
// k6: layer-1 aggregation + bias + LayerNorm + leaky(0.01).  One wave/node.
// ---------------------------------------------------------------------------
__global__ __launch_bounds__(256) void k_agg_ln(
    const float* __restrict__ hp, const float* __restrict__ al_s,
    const float* __restrict__ al_d, const int* __restrict__ offsets,
    const int* __restrict__ csr_src, const float* __restrict__ b1,
    const float* __restrict__ ln_g, const float* __restrict__ ln_b,
    float* __restrict__ h1) {
  int node = blockIdx.x * 4 + (threadIdx.x >> 6);
  int lane = threadIdx.x & 63;
  if (node >= NN) return;
  int off = offsets[node];
  int deg = offsets[node + 1] - off;
  const float2* al2 = (const float2*)al_s;
  float2 aldv = ((const float2*)al_d)[node];
  float ald0 = aldv.x, ald1 = aldv.y;

  float m0, s0, m1, s1;
  softmax_stats(al2, csr_src, off, deg, lane, ald0, ald1, m0, s0, m1, s1);
  float inv0 = 1.f / s0, inv1 = 1.f / s1;

  float4 o0, o1;
  aggregate((const float4*)hp, al2, csr_src, off, deg, lane,
            ald0, ald1, m0, inv0, m1, inv1, o0, o1);

  const float4* b14 = (const float4*)b1;
  float4 bb = b14[lane];
  o0.x += bb.x; o0.y += bb.y; o0.z += bb.z; o0.w += bb.w;
  if (lane < 11) {
    float4 bc = b14[64 + lane];
    o1.x += bc.x; o1.y += bc.y; o1.z += bc.z; o1.w += bc.w;
  }
  float part = o0.x + o0.y + o0.z + o0.w;
  if (lane < 11) part += o1.x + o1.y + o1.z + o1.w;
  #pragma unroll
  for (int o = 32; o > 0; o >>= 1) part += __shfl_xor(part, o, 64);
  float mu = part * (1.f / HC);
  float vp = (o0.x - mu) * (o0.x - mu) + (o0.y - mu) * (o0.y - mu) +
             (o0.z - mu) * (o0.z - mu) + (o0.w - mu) * (o0.w - mu);
  if (lane < 11)
    vp += (o1.x - mu) * (o1.x - mu) + (o1.y - mu) * (o1.y - mu) +
          (o1.z - mu) * (o1.z - mu) + (o1.w - mu) * (o1.w - mu);
  #pragma unroll
  for (int o = 32; o > 0; o >>= 1) vp += __shfl_xor(vp, o, 64);
  float rstd = 1.f / sqrtf(vp * (1.f / HC) + LN_EPS);

  const float4* g4 = (const float4*)ln_g;
  const float4* lb4 = (const float4*)ln_b;
  float4* h14 = (float4*)(h1 + (size_t)node * HC);
  float4 g = g4[lane], lb = lb4[lane], w;
  w.x = lrelu((o0.x - mu) * rstd * g.x + lb.x, 0.01f);
  w.y = lrelu((o0.y - mu) * rstd * g.y + lb.y, 0.01f);
  w.z = lrelu((o0.z - mu) * rstd * g.z + lb.z, 0.01f);
  w.w = lrelu((o0.w - mu) * rstd * g.w + lb.w, 0.01f);
  h14[lane] = w;
  if (lane < 11) {
    float4 g1 = g4[64 + lane], lb1 = lb4[64 + lane], w1;
    w1.x = lrelu((o1.x - mu) * rstd * g1.x + lb1.x, 0.01f);
    w1.y = lrelu((o1.y - mu) * rstd * g1.y + lb1.y, 0.01f);
    w1.z = lrelu((o1.z - mu) * rstd * g1.z + lb1.z, 0.01f);
    w1.w = lrelu((o1.w - mu) * rstd * g1.w + lb1.w, 0.01f);
    h14[64 + lane] = w1;
  }
}

// ---------------------------------------------------------------------------
// k8: layer-2 aggregation + bias + leaky(0.01) + fc projection. One wave/node.
// ---------------------------------------------------------------------------
__global__ __launch_bounds__(256) void k_agg_fc(
    const float* __restrict__ hp, const float* __restrict__ al_s,
    const float* __restrict__ al_d, const int* __restrict__ offsets,
    const int* __restrict__ csr_src, const float* __restrict__ b2,
    const float* __restrict__ fc_w, const float* __restrict__ fc_b,
    float* __restrict__ outp) {
  int node = blockIdx.x * 4 + (threadIdx.x >> 6);
  int lane = threadIdx.x & 63;
  if (node >= NN) return;
  int off = offsets[node];
  int deg = offsets[node + 1] - off;
  const float2* al2 = (const float2*)al_s;
  float2 aldv = ((const float2*)al_d)[node];
  float ald0 = aldv.x, ald1 = aldv.y;

  float m0, s0, m1, s1;
  softmax_stats(al2, csr_src, off, deg, lane, ald0, ald1, m0, s0, m1, s1);
  float inv0 = 1.f / s0, inv1 = 1.f / s1;

  float4 o0, o1;
  aggregate((const float4*)hp, al2, csr_src, off, deg, lane,
            ald0, ald1, m0, inv0, m1, inv1, o0, o1);

  const float4* b24 = (const float4*)b2;
  const float4* f4 = (const float4*)fc_w;
  float4 bb = b24[lane], fw = f4[lane];
  float acc = lrelu(o0.x + bb.x, 0.01f) * fw.x +
              lrelu(o0.y + bb.y, 0.01f) * fw.y +
              lrelu(o0.z + bb.z, 0.01f) * fw.z +
              lrelu(o0.w + bb.w, 0.01f) * fw.w;
  if (lane < 11) {
    float4 bc = b24[64 + lane], fc = f4[64 + lane];
    acc += lrelu(o1.x + bc.x, 0.01f) * fc.x +
           lrelu(o1.y + bc.y, 0.01f) * fc.y +
           lrelu(o1.z + bc.z, 0.01f) * fc.z +
           lrelu(o1.w + bc.w, 0.01f) * fc.w;
  }
  #pragma unroll
  for (int o = 32; o > 0; o >>= 1) acc += __shfl_xor(acc, o, 64);
  if (lane == 0) outp[node] = acc + fc_b[0];
}

// ---------------------------------------------------------------------------
static inline size_t align_up(size_t x, size_t a) { return (x + a - 1) & ~(a - 1); }

extern "C" void kernel_launch(void* const* d_in, const int* in_sizes, int n_in,
                              void* d_out, int out_size, void* d_ws, size_t ws_size,
                              hipStream_t stream) {
  const float* x    = (const float*)d_in[0];
  const int*   ei   = (const int*)d_in[1];
  // d_in[2] edge_weight: unused by reference
  const float* emb  = (const float*)d_in[3];
  const float* W1   = (const float*)d_in[4];
  const float* as1  = (const float*)d_in[5];
  const float* ad1  = (const float*)d_in[6];
  const float* b1   = (const float*)d_in[7];
  const float* ln_g = (const float*)d_in[8];
  const float* ln_b = (const float*)d_in[9];
  const float* W2   = (const float*)d_in[10];
  const float* as2  = (const float*)d_in[11];
  const float* ad2  = (const float*)d_in[12];
  const float* b2   = (const float*)d_in[13];
  const float* fc_w = (const float*)d_in[14];
  const float* fc_b = (const float*)d_in[15];
  float* outp = (float*)d_out;

  constexpr int KS1 = (DD + 31) / 32;   // 5
  constexpr int KS2 = (HC + 31) / 32;   // 10

  // workspace layout (h0 shares the h1 region: lifetimes are disjoint)
  char* ws = (char*)d_ws;
  size_t o = 0;
  size_t o_hp  = o; o = align_up(o + (size_t)NN * HC * 4, 256);   // 60 MB
  size_t o_h1  = o; o = align_up(o + (size_t)NN * HC * 4, 256);   // 60 MB (h0 aliases)
  size_t o_als = o; o = align_up(o + (size_t)NN * 2 * 4, 256);
  size_t o_ald = o; o = align_up(o + (size_t)NN * 2 * 4, 256);
  size_t o_cnt = o; o = align_up(o + (size_t)NN * 4, 256);
  size_t o_cur = o; o = align_up(o + (size_t)NN * 4, 256);
  size_t o_off = o; o = align_up(o + (size_t)(NN + 1) * 4, 256);
  size_t o_csr = o; o = align_up(o + (size_t)ET * 4, 256);
  size_t o_wp1 = o; o = align_up(o + (size_t)KS1 * NT * 64 * 8 * 2, 256);
  size_t o_wp2 = o; o = align_up(o + (size_t)KS2 * NT * 64 * 8 * 2, 256);
  size_t o_va1 = o; o = align_up(o + (size_t)4 * DD * 4, 256);
  size_t o_va2 = o; o = align_up(o + (size_t)4 * HC * 4, 256);

  float* hp      = (float*)(ws + o_hp);
  float* h1      = (float*)(ws + o_h1);
  float* h0      = (float*)(ws + o_h1);  // alias
  float* al_s    = (float*)(ws + o_als);
  float* al_d    = (float*)(ws + o_ald);
  int*   counts  = (int*)(ws + o_cnt);
  int*   cursor  = (int*)(ws + o_cur);
  int*   offsets = (int*)(ws + o_off);
  int*   csr_src = (int*)(ws + o_csr);
  unsigned short* Wp1 = (unsigned short*)(ws + o_wp1);
  unsigned short* Wp2 = (unsigned short*)(ws + o_wp2);
  float* va1     = (float*)(ws + o_va1);
  float* va2     = (float*)(ws + o_va2);

  hipMemsetAsync(ws + o_cnt, 0, o_off - o_cnt, stream);

  const int nwave_blocks = (NN + 3) / 4;          // 12500
  const int edge_blocks  = (ET + 255) / 256;      // 3321
  const int gemm_blocks  = (NN + 63) / 64;        // 782

  // embedding gather + CSR build + weight prep (independent)
  k_argmax_embed<<<nwave_blocks, 256, 0, stream>>>(x, emb, h0);
  k_count<<<edge_blocks, 256, 0, stream>>>(ei, counts);
  k_scan<<<1, 1024, 0, stream>>>(counts, offsets);
  k_scatter<<<edge_blocks, 256, 0, stream>>>(ei, offsets, cursor, csr_src);
  k_pack_w<<<KS1 * NT, 64, 0, stream>>>(W1, Wp1, DD);
  k_pack_w<<<KS2 * NT, 64, 0, stream>>>(W2, Wp2, HC);
  k_wa<<<(DD + 63) / 64, 64, 0, stream>>>(W1, as1, ad1, va1, DD);
  k_wa<<<(HC + 63) / 64, 64, 0, stream>>>(W2, as2, ad2, va2, HC);

  // ---- layer 1 ----
  k_gemm_mfma<DD><<<gemm_blocks, 256, 0, stream>>>(h0, Wp1, hp);
  k_attn_va<DD><<<nwave_blocks, 256, 0, stream>>>(h0, va1, al_s, al_d);
  k_agg_ln<<<nwave_blocks, 256, 0, stream>>>(hp, al_s, al_d, offsets, csr_src,
                                             b1, ln_g, ln_b, h1);

  // ---- layer 2 ----
  k_gemm_mfma<HC><<<gemm_blocks, 256, 0, stream>>>(h1, Wp2, hp);
  k_attn_va<HC><<<nwave_blocks, 256, 0, stream>>>(h1, va2, al_s, al_d);
  k_agg_fc<<<nwave_blocks, 256, 0, stream>>>(hp, al_s, al_d, offsets, csr_src,
                                             b2, fc_w, fc_b, outp);
}

// Round 6
// 695.450 us; speedup vs baseline: 1.5451x; 1.1507x over previous
//
#include <hip/hip_runtime.h>
#include <hip/hip_bf16.h>
#include <math.h>

// Problem constants (from reference)
#define NN 50000
#define EE 800000
#define FIN 256
#define DD 150
#define HC 300        // H*C
#define CC 150
#define ET (EE + NN)  // edges + self loops = 850000
#define LN_EPS 1e-5f
#define NT 19         // col tiles of 16 covering 300 (304)

typedef __attribute__((ext_vector_type(8))) short short8;   // 8 bf16 (4 VGPR)
typedef __attribute__((ext_vector_type(4))) float f32x4;    // MFMA C/D frag
typedef unsigned short u16;
typedef unsigned int u32;

static __device__ __forceinline__ u16 f2bf(float f) {
  u32 u = __float_as_uint(f);
  u += 0x7FFFu + ((u >> 16) & 1u);   // round-to-nearest-even
  return (u16)(u >> 16);
}
static __device__ __forceinline__ float bflo(u32 u) {
  return __uint_as_float(u << 16);
}
static __device__ __forceinline__ float bfhi(u32 u) {
  return __uint_as_float(u & 0xFFFF0000u);
}

// ---------------------------------------------------------------------------
// k1: idx = argmax(x, axis=1); h0b = bf16(emb[idx])   (one wave per node)
// ---------------------------------------------------------------------------
__global__ __launch_bounds__(256) void k_argmax_embed(
    const float* __restrict__ x, const float* __restrict__ emb,
    u16* __restrict__ h0b) {
  int node = blockIdx.x * 4 + (threadIdx.x >> 6);
  int lane = threadIdx.x & 63;
  if (node >= NN) return;
  const float* row = x + (size_t)node * FIN;
  float best = -INFINITY;
  int bidx = FIN;
  #pragma unroll
  for (int r = 0; r < FIN / 64; ++r) {
    int j = lane + 64 * r;
    float v = row[j];
    if (v > best || (v == best && j < bidx)) { best = v; bidx = j; }
  }
  #pragma unroll
  for (int off = 32; off > 0; off >>= 1) {
    float ov = __shfl_xor(best, off, 64);
    int   oi = __shfl_xor(bidx, off, 64);
    if (ov > best || (ov == best && oi < bidx)) { best = ov; bidx = oi; }
  }
  // 150 f32 -> 75 uints of 2 bf16
  const float2* e2 = (const float2*)(emb + (size_t)bidx * DD);
  u32* o = (u32*)(h0b + (size_t)node * DD);
  float2 v = e2[lane];
  o[lane] = (u32)f2bf(v.x) | ((u32)f2bf(v.y) << 16);
  if (lane < 11) {
    float2 w = e2[64 + lane];
    o[64 + lane] = (u32)f2bf(w.x) | ((u32)f2bf(w.y) << 16);
  }
}

// ---------------------------------------------------------------------------
// CSR build (count / scan / scatter)
// ---------------------------------------------------------------------------
__global__ __launch_bounds__(256) void k_count(
    const int* __restrict__ ei, int* __restrict__ counts) {
  int et = blockIdx.x * blockDim.x + threadIdx.x;
  if (et >= ET) return;
  int d = (et < EE) ? ei[EE + et] : (et - EE);
  atomicAdd(&counts[d], 1);
}

__global__ __launch_bounds__(1024) void k_scan(
    const int* __restrict__ counts, int* __restrict__ offsets) {
  __shared__ int buf[1024];
  const int CH = 49;  // 1024*49 >= NN
  int tid = threadIdx.x;
  int base = tid * CH;
  int lsum = 0;
  for (int c = 0; c < CH; ++c) {
    int i = base + c;
    if (i < NN) lsum += counts[i];
  }
  buf[tid] = lsum;
  __syncthreads();
  for (int off = 1; off < 1024; off <<= 1) {
    int t = (tid >= off) ? buf[tid - off] : 0;
    __syncthreads();
    buf[tid] += t;
    __syncthreads();
  }
  int incl = buf[tid];
  int run = incl - lsum;
  for (int c = 0; c < CH; ++c) {
    int i = base + c;
    if (i < NN) { offsets[i] = run; run += counts[i]; }
  }
  if (tid == 1023) offsets[NN] = incl;
}

__global__ __launch_bounds__(256) void k_scatter(
    const int* __restrict__ ei, const int* __restrict__ offsets,
    int* __restrict__ cursor, int* __restrict__ csr_src) {
  int et = blockIdx.x * blockDim.x + threadIdx.x;
  if (et >= ET) return;
  int s = (et < EE) ? ei[et] : (et - EE);
  int d = (et < EE) ? ei[EE + et] : (et - EE);
  int pos = offsets[d] + atomicAdd(&cursor[d], 1);
  csr_src[pos] = s;
}

// ---------------------------------------------------------------------------
// k_pack_w: W [K][300] f32 -> Wp bf16 B-fragment layout [ks][ct][lane][8]
// Wp[((ks*NT+ct)*64+l)*8 + j] = W[ks*32+(l>>4)*8+j][ct*16+(l&15)]
// ---------------------------------------------------------------------------
__global__ __launch_bounds__(64) void k_pack_w(
    const float* __restrict__ W, u16* __restrict__ Wp, int K) {
  int ks = blockIdx.x / NT, ct = blockIdx.x % NT;
  int l = threadIdx.x;
  int col = ct * 16 + (l & 15);
  int kb = ks * 32 + ((l >> 4) << 3);
  u16 v[8];
  #pragma unroll
  for (int j = 0; j < 8; ++j) {
    int k = kb + j;
    float f = (k < K && col < HC) ? W[(size_t)k * HC + col] : 0.f;
    v[j] = f2bf(f);
  }
  *(ulonglong2*)(Wp + ((size_t)blockIdx.x * 64 + l) * 8) = *(ulonglong2*)v;
}

// ---------------------------------------------------------------------------
// k_gemm_mfma: hp(bf16) = h(bf16) @ W via mfma_f32_16x16x32_bf16, with fused
// attention-coefficient epilogue writing al_s/al_d (f32, from f32 acc).
// Block 256 = 4 waves, 64 rows/block; wave w -> rows [w*16, w*16+16).
// ---------------------------------------------------------------------------
template <int K>
__global__ __launch_bounds__(256) void k_gemm_mfma(
    const u16* __restrict__ h, const u16* __restrict__ Wp,
    const float* __restrict__ a_s, const float* __restrict__ a_d,
    u16* __restrict__ hpb, float* __restrict__ al_s,
    float* __restrict__ al_d) {
  constexpr int KS = (K + 31) / 32;
  constexpr int RS = KS * 32 + 8;     // +8 shorts pad
  constexpr int KU = K / 2;           // uints per row (K even)
  constexpr int ZU = (KS * 32 - K) / 2;
  __shared__ u16 sh[64 * RS];
  int tid = threadIdx.x;
  int wave = tid >> 6, lane = tid & 63;
  int rows0 = blockIdx.x * 64;

  // stage h (already bf16) -> LDS
  const u32* hu = (const u32*)h;
  for (int i = tid; i < 64 * KU; i += 256) {
    int r = i / KU, c = i - r * KU;
    int gr = rows0 + r; if (gr >= NN) gr = NN - 1;
    *(u32*)&sh[r * RS + 2 * c] = hu[(size_t)gr * KU + c];
  }
  for (int i = tid; i < 64 * ZU; i += 256) {   // K-tail zeros
    int r = i / ZU, c = i - r * ZU;
    *(u32*)&sh[r * RS + K + 2 * c] = 0u;
  }
  __syncthreads();

  f32x4 acc[NT];
  #pragma unroll
  for (int ct = 0; ct < NT; ++ct) acc[ct] = f32x4{0.f, 0.f, 0.f, 0.f};

  const u16* abase = &sh[(wave * 16 + (lane & 15)) * RS + (lane >> 4) * 8];
  const short8* wb = (const short8*)Wp;

  short8 a = *(const short8*)abase;
  #pragma unroll 1
  for (int ks = 0; ks < KS; ++ks) {
    short8 an = (ks + 1 < KS) ? *(const short8*)(abase + (ks + 1) * 32) : a;
    #pragma unroll
    for (int ct = 0; ct < NT; ++ct) {
      short8 b = wb[(ks * NT + ct) * 64 + lane];
      acc[ct] = __builtin_amdgcn_mfma_f32_16x16x32_bf16(a, b, acc[ct], 0, 0, 0);
    }
    a = an;
  }

  // C/D layout: col = lane&15, row = (lane>>4)*4 + j   [m89-verified]
  int grow = rows0 + wave * 16 + ((lane >> 4) << 2);
  int cbase = lane & 15;

  float ps0[4] = {0, 0, 0, 0}, ps1[4] = {0, 0, 0, 0};
  float pd0[4] = {0, 0, 0, 0}, pd1[4] = {0, 0, 0, 0};
  #pragma unroll
  for (int ct = 0; ct < NT; ++ct) {
    int col = ct * 16 + cbase;
    bool valid = col < HC;
    bool head0 = col < CC;
    float as_v = valid ? a_s[col] : 0.f;
    float ad_v = valid ? a_d[col] : 0.f;
    #pragma unroll
    for (int j = 0; j < 4; ++j) {
      float v = acc[ct][j];
      int gr = grow + j;
      if (valid && gr < NN) hpb[(size_t)gr * HC + col] = f2bf(v);
      if (head0) { ps0[j] += v * as_v; pd0[j] += v * ad_v; }
      else       { ps1[j] += v * as_v; pd1[j] += v * ad_v; }
    }
  }
  // reduce across the 16 lanes of each row group
  #pragma unroll
  for (int o = 1; o < 16; o <<= 1) {
    #pragma unroll
    for (int j = 0; j < 4; ++j) {
      ps0[j] += __shfl_xor(ps0[j], o, 64);
      ps1[j] += __shfl_xor(ps1[j], o, 64);
      pd0[j] += __shfl_xor(pd0[j], o, 64);
      pd1[j] += __shfl_xor(pd1[j], o, 64);
    }
  }
  if ((lane & 15) == 0) {
    #pragma unroll
    for (int j = 0; j < 4; ++j) {
      int gr = grow + j;
      if (gr < NN) {
        ((float2*)al_s)[gr] = make_float2(ps0[j], ps1[j]);
        ((float2*)al_d)[gr] = make_float2(pd0[j], pd1[j]);
      }
    }
  }
}

__device__ __forceinline__ float lrelu(float v, float sl) {
  return v >= 0.f ? v : sl * v;
}

__device__ __forceinline__ void sm_combine(float& m, float& s, float om, float os) {
  if (om > m) {
    s = s * expf(m - om) + os;
    m = om;
  } else if (os > 0.f) {
    s += os * expf(om - m);
  }
}

// ---------------------------------------------------------------------------
// k_stats_alpha: per-node online-softmax stats, then per-edge alpha writeback.
// One wave per node. alpha2[slot] = {a0, a1} final normalized weights.
// ---------------------------------------------------------------------------
__global__ __launch_bounds__(256) void k_stats_alpha(
    const float* __restrict__ al_s, const float* __restrict__ al_d,
    const int* __restrict__ offsets, const int* __restrict__ csr_src,
    float2* __restrict__ alpha2) {
  int node = blockIdx.x * 4 + (threadIdx.x >> 6);
  int lane = threadIdx.x & 63;
  if (node >= NN) return;
  int off = offsets[node];
  int deg = offsets[node + 1] - off;
  const float2* al2 = (const float2*)al_s;
  float2 aldv = ((const float2*)al_d)[node];
  float ald0 = aldv.x, ald1 = aldv.y;

  float m0 = -INFINITY, s0 = 0.f, m1 = -INFINITY, s1 = 0.f;
  for (int i = lane; i < deg; i += 64) {
    int sn = csr_src[off + i];
    float2 av = al2[sn];
    float e0 = lrelu(av.x + ald0, 0.2f);
    float e1 = lrelu(av.y + ald1, 0.2f);
    if (e0 > m0) { s0 = s0 * expf(m0 - e0) + 1.f; m0 = e0; } else s0 += expf(e0 - m0);
    if (e1 > m1) { s1 = s1 * expf(m1 - e1) + 1.f; m1 = e1; } else s1 += expf(e1 - m1);
  }
  #pragma unroll
  for (int o = 32; o > 0; o >>= 1) {
    float om0 = __shfl_xor(m0, o, 64), os0 = __shfl_xor(s0, o, 64);
    float om1 = __shfl_xor(m1, o, 64), os1 = __shfl_xor(s1, o, 64);
    sm_combine(m0, s0, om0, os0);
    sm_combine(m1, s1, om1, os1);
  }
  float inv0 = 1.f / s0, inv1 = 1.f / s1;

  for (int i = lane; i < deg; i += 64) {
    int sn = csr_src[off + i];
    float2 av = al2[sn];          // L1/L2 hit (just gathered)
    float e0 = lrelu(av.x + ald0, 0.2f);
    float e1 = lrelu(av.y + ald1, 0.2f);
    alpha2[off + i] = make_float2(expf(e0 - m0) * inv0, expf(e1 - m1) * inv1);
  }
}

// ---------------------------------------------------------------------------
// pass B: weighted bf16-row aggregation; alpha precomputed (wave-uniform loads).
// Lane j owns cols 4j..4j+3 (uint2 = 4 bf16) and cols 256+4j.. for j<11.
// ---------------------------------------------------------------------------
__device__ __forceinline__ void agg_b(
    const u16* __restrict__ hpb, const int* __restrict__ csr_src,
    const float2* __restrict__ alpha2, int off, int deg, int lane,
    float4& o0, float4& o1) {
  o0 = make_float4(0.f, 0.f, 0.f, 0.f);
  o1 = make_float4(0.f, 0.f, 0.f, 0.f);
  int c0 = lane * 4;
  bool t0 = c0 + 0 < CC, t1 = c0 + 1 < CC, t2 = c0 + 2 < CC, t3 = c0 + 3 < CC;
  bool hi = lane < 11;

  int sn = csr_src[off];
  float2 al = alpha2[off];
  const uint2* rp = (const uint2*)(hpb + (size_t)sn * HC);
  uint2 u = rp[lane];
  uint2 ut = make_uint2(0u, 0u);
  if (hi) ut = rp[64 + lane];

  for (int i = 0; i < deg; ++i) {
    float2 nal = make_float2(0.f, 0.f);
    uint2 nu = make_uint2(0u, 0u), nut = make_uint2(0u, 0u);
    if (i + 1 < deg) {            // prefetch next row
      int nsn = csr_src[off + i + 1];
      nal = alpha2[off + i + 1];
      const uint2* nrp = (const uint2*)(hpb + (size_t)nsn * HC);
      nu = nrp[lane];
      if (hi) nut = nrp[64 + lane];
    }
    float a0 = al.x, a1 = al.y;
    o0.x += bflo(u.x) * (t0 ? a0 : a1);
    o0.y += bfhi(u.x) * (t1 ? a0 : a1);
    o0.z += bflo(u.y) * (t2 ? a0 : a1);
    o0.w += bfhi(u.y) * (t3 ? a0 : a1);
    o1.x += bflo(ut.x) * a1;      // ut stays 0 for lane>=11
    o1.y += bfhi(ut.x) * a1;
    o1.z += bflo(ut.y) * a1;
    o1.w += bfhi(ut.y) * a1;
    u = nu; ut = nut; al = nal;
  }
}

// ---------------------------------------------------------------------------
// k_agg_ln: layer-1 pass B + bias + LayerNorm + leaky(0.01) -> h1b (bf16)
// ---------------------------------------------------------------------------
__global__ __launch_bounds__(256) void k_agg_ln(
    const u16* __restrict__ hpb, const int* __restrict__ offsets,
    const int* __restrict__ csr_src, const float2* __restrict__ alpha2,
    const float* __restrict__ b1, const float* __restrict__ ln_g,
    const float* __restrict__ ln_b, u16* __restrict__ h1b) {
  int node = blockIdx.x * 4 + (threadIdx.x >> 6);
  int lane = threadIdx.x & 63;
  if (node >= NN) return;
  int off = offsets[node];
  int deg = offsets[node + 1] - off;

  float4 o0, o1;
  agg_b(hpb, csr_src, alpha2, off, deg, lane, o0, o1);

  const float4* b14 = (const float4*)b1;
  float4 bb = b14[lane];
  o0.x += bb.x; o0.y += bb.y; o0.z += bb.z; o0.w += bb.w;
  if (lane < 11) {
    float4 bc = b14[64 + lane];
    o1.x += bc.x; o1.y += bc.y; o1.z += bc.z; o1.w += bc.w;
  }
  float part = o0.x + o0.y + o0.z + o0.w;
  if (lane < 11) part += o1.x + o1.y + o1.z + o1.w;
  #pragma unroll
  for (int o = 32; o > 0; o >>= 1) part += __shfl_xor(part, o, 64);
  float mu = part * (1.f / HC);
  float vp = (o0.x - mu) * (o0.x - mu) + (o0.y - mu) * (o0.y - mu) +
             (o0.z - mu) * (o0.z - mu) + (o0.w - mu) * (o0.w - mu);
  if (lane < 11)
    vp += (o1.x - mu) * (o1.x - mu) + (o1.y - mu) * (o1.y - mu) +
          (o1.z - mu) * (o1.z - mu) + (o1.w - mu) * (o1.w - mu);
  #pragma unroll
  for (int o = 32; o > 0; o >>= 1) vp += __shfl_xor(vp, o, 64);
  float rstd = 1.f / sqrtf(vp * (1.f / HC) + LN_EPS);

  const float4* g4 = (const float4*)ln_g;
  const float4* lb4 = (const float4*)ln_b;
  u32* h1u = (u32*)(h1b + (size_t)node * HC);
  float4 g = g4[lane], lb = lb4[lane];
  float wx = lrelu((o0.x - mu) * rstd * g.x + lb.x, 0.01f);
  float wy = lrelu((o0.y - mu) * rstd * g.y + lb.y, 0.01f);
  float wz = lrelu((o0.z - mu) * rstd * g.z + lb.z, 0.01f);
  float ww = lrelu((o0.w - mu) * rstd * g.w + lb.w, 0.01f);
  h1u[2 * lane + 0] = (u32)f2bf(wx) | ((u32)f2bf(wy) << 16);
  h1u[2 * lane + 1] = (u32)f2bf(wz) | ((u32)f2bf(ww) << 16);
  if (lane < 11) {
    float4 g1 = g4[64 + lane], lb1 = lb4[64 + lane];
    float vx = lrelu((o1.x - mu) * rstd * g1.x + lb1.x, 0.01f);
    float vy = lrelu((o1.y - mu) * rstd * g1.y + lb1.y, 0.01f);
    float vz = lrelu((o1.z - mu) * rstd * g1.z + lb1.z, 0.01f);
    float vw = lrelu((o1.w - mu) * rstd * g1.w + lb1.w, 0.01f);
    h1u[2 * (64 + lane) + 0] = (u32)f2bf(vx) | ((u32)f2bf(vy) << 16);
    h1u[2 * (64 + lane) + 1] = (u32)f2bf(vz) | ((u32)f2bf(vw) << 16);
  }
}

// ---------------------------------------------------------------------------
// k_agg_fc: layer-2 pass B + bias + leaky(0.01) + fc projection -> out (f32)
// ---------------------------------------------------------------------------
__global__ __launch_bounds__(256) void k_agg_fc(
    const u16* __restrict__ hpb, const int* __restrict__ offsets,
    const int* __restrict__ csr_src, const float2* __restrict__ alpha2,
    const float* __restrict__ b2, const float* __restrict__ fc_w,
    const float* __restrict__ fc_b, float* __restrict__ outp) {
  int node = blockIdx.x * 4 + (threadIdx.x >> 6);
  int lane = threadIdx.x & 63;
  if (node >= NN) return;
  int off = offsets[node];
  int deg = offsets[node + 1] - off;

  float4 o0, o1;
  agg_b(hpb, csr_src, alpha2, off, deg, lane, o0, o1);

  const float4* b24 = (const float4*)b2;
  const float4* f4 = (const float4*)fc_w;
  float4 bb = b24[lane], fw = f4[lane];
  float acc = lrelu(o0.x + bb.x, 0.01f) * fw.x +
              lrelu(o0.y + bb.y, 0.01f) * fw.y +
              lrelu(o0.z + bb.z, 0.01f) * fw.z +
              lrelu(o0.w + bb.w, 0.01f) * fw.w;
  if (lane < 11) {
    float4 bc = b24[64 + lane], fc = f4[64 + lane];
    acc += lrelu(o1.x + bc.x, 0.01f) * fc.x +
           lrelu(o1.y + bc.y, 0.01f) * fc.y +
           lrelu(o1.z + bc.z, 0.01f) * fc.z +
           lrelu(o1.w + bc.w, 0.01f) * fc.w;
  }
  #pragma unroll
  for (int o = 32; o > 0; o >>= 1) acc += __shfl_xor(acc, o, 64);
  if (lane == 0) outp[node] = acc + fc_b[0];
}

// ---------------------------------------------------------------------------
static inline size_t align_up(size_t x, size_t a) { return (x + a - 1) & ~(a - 1); }

extern "C" void kernel_launch(void* const* d_in, const int* in_sizes, int n_in,
                              void* d_out, int out_size, void* d_ws, size_t ws_size,
                              hipStream_t stream) {
  const float* x    = (const float*)d_in[0];
  const int*   ei   = (const int*)d_in[1];
  // d_in[2] edge_weight: unused by reference
  const float* emb  = (const float*)d_in[3];
  const float* W1   = (const float*)d_in[4];
  const float* as1  = (const float*)d_in[5];
  const float* ad1  = (const float*)d_in[6];
  const float* b1   = (const float*)d_in[7];
  const float* ln_g = (const float*)d_in[8];
  const float* ln_b = (const float*)d_in[9];
  const float* W2   = (const float*)d_in[10];
  const float* as2  = (const float*)d_in[11];
  const float* ad2  = (const float*)d_in[12];
  const float* b2   = (const float*)d_in[13];
  const float* fc_w = (const float*)d_in[14];
  const float* fc_b = (const float*)d_in[15];
  float* outp = (float*)d_out;

  constexpr int KS1 = (DD + 31) / 32;   // 5
  constexpr int KS2 = (HC + 31) / 32;   // 10

  // workspace layout
  char* ws = (char*)d_ws;
  size_t o = 0;
  size_t o_hpb = o; o = align_up(o + (size_t)NN * HC * 2, 256);   // 30 MB bf16
  size_t o_h1b = o; o = align_up(o + (size_t)NN * HC * 2, 256);   // 30 MB (h0b aliases)
  size_t o_als = o; o = align_up(o + (size_t)NN * 2 * 4, 256);
  size_t o_ald = o; o = align_up(o + (size_t)NN * 2 * 4, 256);
  size_t o_alp = o; o = align_up(o + (size_t)ET * 8, 256);        // 6.8 MB
  size_t o_cnt = o; o = align_up(o + (size_t)NN * 4, 256);
  size_t o_cur = o; o = align_up(o + (size_t)NN * 4, 256);
  size_t o_off = o; o = align_up(o + (size_t)(NN + 1) * 4, 256);
  size_t o_csr = o; o = align_up(o + (size_t)ET * 4, 256);
  size_t o_wp1 = o; o = align_up(o + (size_t)KS1 * NT * 64 * 8 * 2, 256);
  size_t o_wp2 = o; o = align_up(o + (size_t)KS2 * NT * 64 * 8 * 2, 256);

  u16*   hpb     = (u16*)(ws + o_hpb);
  u16*   h1b     = (u16*)(ws + o_h1b);
  u16*   h0b     = (u16*)(ws + o_h1b);  // alias: h0 dead before h1 written
  float* al_s    = (float*)(ws + o_als);
  float* al_d    = (float*)(ws + o_ald);
  float2* alpha2 = (float2*)(ws + o_alp);
  int*   counts  = (int*)(ws + o_cnt);
  int*   cursor  = (int*)(ws + o_cur);
  int*   offsets = (int*)(ws + o_off);
  int*   csr_src = (int*)(ws + o_csr);
  u16*   Wp1     = (u16*)(ws + o_wp1);
  u16*   Wp2     = (u16*)(ws + o_wp2);

  hipMemsetAsync(ws + o_cnt, 0, o_off - o_cnt, stream);  // counts + cursor

  const int nwave_blocks = (NN + 3) / 4;          // 12500
  const int edge_blocks  = (ET + 255) / 256;      // 3321
  const int gemm_blocks  = (NN + 63) / 64;        // 782

  // embedding gather + CSR build + weight prep
  k_argmax_embed<<<nwave_blocks, 256, 0, stream>>>(x, emb, h0b);
  k_count<<<edge_blocks, 256, 0, stream>>>(ei, counts);
  k_scan<<<1, 1024, 0, stream>>>(counts, offsets);
  k_scatter<<<edge_blocks, 256, 0, stream>>>(ei, offsets, cursor, csr_src);
  k_pack_w<<<KS1 * NT, 64, 0, stream>>>(W1, Wp1, DD);
  k_pack_w<<<KS2 * NT, 64, 0, stream>>>(W2, Wp2, HC);

  // ---- layer 1 ----
  k_gemm_mfma<DD><<<gemm_blocks, 256, 0, stream>>>(h0b, Wp1, as1, ad1,
                                                   hpb, al_s, al_d);
  k_stats_alpha<<<nwave_blocks, 256, 0, stream>>>(al_s, al_d, offsets,
                                                  csr_src, alpha2);
  k_agg_ln<<<nwave_blocks, 256, 0, stream>>>(hpb, offsets, csr_src, alpha2,
                                             b1, ln_g, ln_b, h1b);

  // ---- layer 2 ----
  k_gemm_mfma<HC><<<gemm_blocks, 256, 0, stream>>>(h1b, Wp2, as2, ad2,
                                                   hpb, al_s, al_d);
  k_stats_alpha<<<nwave_blocks, 256, 0, stream>>>(al_s, al_d, offsets,
                                                  csr_src, alpha2);
  k_agg_fc<<<nwave_blocks, 256, 0, stream>>>(hpb, offsets, csr_src, alpha2,
                                             b2, fc_w, fc_b, outp);
}